// Round 4
// baseline (8245.667 us; speedup 1.0000x reference)
//
#include <hip/hip_runtime.h>

#define T_STEPS 784
#define H 512
#define NBATCH 128
#define OUTC 10
#define ZROW 512   // zero-row index appended to W2T/W3T

// out layout (floats): outputs[128*10] | fr1[128*512] | fr2 | fr3 | layer_fr[3]
#define OFF_OUT   0
#define OFF_FR1   1280
#define OFF_FR2   66816
#define OFF_FR3   132352
#define OFF_LFR   197888

__global__ __launch_bounds__(256) void prep_kernel(
    const float* __restrict__ W2, const float* __restrict__ W3,
    const float* __restrict__ m1, const float* __restrict__ m2, const float* __restrict__ m3,
    float* __restrict__ W2T, float* __restrict__ W3T,
    unsigned char* __restrict__ mP, float* __restrict__ out_tail)
{
    int tid = blockIdx.x * blockDim.x + threadIdx.x;
    int stride = gridDim.x * blockDim.x;
    for (int p = tid; p < H * H; p += stride) {
        int i = p >> 9, j = p & (H - 1);
        W2T[p] = W2[j * H + i];
        W3T[p] = W3[j * H + i];
    }
    for (int p = tid; p < H; p += stride) {
        W2T[H * H + p] = 0.f;
        W3T[H * H + p] = 0.f;
    }
    for (int p = tid; p < T_STEPS * H; p += stride) {
        int t = p >> 9, i = p & (H - 1);
        unsigned char b = 0;
        if (m1[i * T_STEPS + t] != 0.f) b |= 1;
        if (m2[i * T_STEPS + t] != 0.f) b |= 2;
        if (m3[i * T_STEPS + t] != 0.f) b |= 4;
        mP[p] = b;
    }
    if (tid < 3) out_tail[tid] = 0.f;
}

__device__ __forceinline__ void gather64(const short* lp, const float* __restrict__ Wp,
                                         float* a)
{
    const short4* q = (const short4*)lp;
    float g[64];
    #pragma unroll
    for (int i = 0; i < 16; ++i) {
        short4 s = q[i];
        g[4*i+0] = Wp[(int)s.x << 9];
        g[4*i+1] = Wp[(int)s.y << 9];
        g[4*i+2] = Wp[(int)s.z << 9];
        g[4*i+3] = Wp[(int)s.w << 9];
    }
    #pragma unroll
    for (int i = 0; i < 64; ++i) a[i & 7] += g[i];
}

__device__ __forceinline__ void gather32(const short* lp, const float* __restrict__ Wp,
                                         float* a)
{
    const short4* q = (const short4*)lp;
    float g[32];
    #pragma unroll
    for (int i = 0; i < 8; ++i) {
        short4 s = q[i];
        g[4*i+0] = Wp[(int)s.x << 9];
        g[4*i+1] = Wp[(int)s.y << 9];
        g[4*i+2] = Wp[(int)s.z << 9];
        g[4*i+3] = Wp[(int)s.w << 9];
    }
    #pragma unroll
    for (int i = 0; i < 32; ++i) a[i & 7] += g[i];
}

__global__ __launch_bounds__(1024, 4) void snn_kernel(
    const float* __restrict__ x,
    const float* __restrict__ W1, const float* __restrict__ b1,
    const float* __restrict__ b2, const float* __restrict__ b3,
    const float* __restrict__ W4, const float* __restrict__ b4,
    const float* __restrict__ W2T, const float* __restrict__ W3T,
    const unsigned char* __restrict__ mP,
    float* __restrict__ out)
{
    const int n = blockIdx.x;          // sample
    const int tid = threadIdx.x;
    const int h = tid >> 9;            // half: 0 or 1 (split-K over firing list)
    const int j = tid & (H - 1);       // neuron
    const int lane = tid & 63;
    const int wid = tid >> 6;          // 0..15; h==0 <=> wid<8

    __shared__ float x_lds[T_STEPS];
    __shared__ short list1[H + 64];
    __shared__ short list2[H + 64];
    __shared__ int wcnt1[8], wcnt2[8];
    __shared__ float pacc[H];
    __shared__ float acc10[16];
    __shared__ float rsum[3];

    for (int t = tid; t < T_STEPS; t += 1024) x_lds[t] = x[n * T_STEPS + t];

    float mem1 = 0.f, mem2 = 0.f, mem3 = 0.f;
    float s1 = 0.f, s2 = 0.f, s3 = 0.f;
    float c1 = 0.f, c2 = 0.f, c3 = 0.f;
    float w1 = 0.f, b1v = 0.f, b2v = 0.f, b3v = 0.f;
    if (h == 0) { w1 = W1[j]; b1v = b1[j]; b2v = b2[j]; b3v = b3[j]; }
    const unsigned long long lt_mask = (1ull << lane) - 1ull;
    const float* __restrict__ Wp2 = W2T + j;
    const float* __restrict__ Wp3 = W3T + j;

    unsigned char mb = mP[j];   // masks for t=0 (both halves read same byte)
    __syncthreads();

    for (int t = 0; t < T_STEPS; ++t) {
        const bool k1 = (mb & 1) != 0;
        const bool k2 = (mb & 2) != 0;
        const bool k3 = (mb & 4) != 0;

        // ---- Layer 1 (elementwise, h0 only) ----
        if (h == 0) {
            float nm1 = mem1 * (0.2f * (1.f - s1)) + x_lds[t] * w1 + b1v;
            if (k1) mem1 = nm1;
            bool f1 = k1 && (mem1 > 0.5f);
            s1 = f1 ? 1.f : 0.f;  c1 += s1;
            unsigned long long ball = __ballot(f1);
            if (lane == 0) wcnt1[wid] = __popcll(ball);
        }
        // prefetch next step's masks (all threads; flies under the gathers)
        int tn = (t + 1 < T_STEPS) ? t + 1 : t;
        unsigned char mbn = mP[tn * H + j];

        __syncthreads();   // A1: wcnt1 visible
        int cnt1 = 0, base1 = 0;
        #pragma unroll
        for (int w = 0; w < 8; ++w) {
            int c = wcnt1[w];
            if (w < (wid & 7)) base1 += c;
            cnt1 += c;
        }
        if (h == 0) {
            bool f1 = s1 > 0.f;
            unsigned long long ball = __ballot(f1);
            int pos = __popcll(ball & lt_mask);
            if (f1) list1[base1 + pos] = (short)j;
            int cntp = (cnt1 + 63) & ~63;
            if (j < cntp - cnt1) list1[cnt1 + j] = ZROW;
        }
        __syncthreads();   // B1: list1 ready (padded to x64)

        // ---- Layer 2 gather: split-K across halves ----
        {
            int cntp = (cnt1 + 63) & ~63;
            int hsz = cntp >> 1;              // multiple of 32
            int s0 = h * hsz, e0 = s0 + hsz;
            float a[8] = {0.f,0.f,0.f,0.f,0.f,0.f,0.f,0.f};
            if (k2) {
                int r = s0;
                for (; r + 64 <= e0; r += 64) gather64(list1 + r, Wp2, a);
                if (r < e0) gather32(list1 + r, Wp2, a);
            }
            float sx = ((a[0]+a[1])+(a[2]+a[3])) + ((a[4]+a[5])+(a[6]+a[7]));
            if (h) pacc[j] = sx;
            __syncthreads();   // C2: partials ready
            if (h == 0) {
                sx += pacc[j];
                float nm2 = mem2 * (0.2f * (1.f - s2)) + sx + b2v;
                if (k2) mem2 = nm2;
                bool f2 = k2 && (mem2 > 0.5f);
                s2 = f2 ? 1.f : 0.f;  c2 += s2;
                unsigned long long ball = __ballot(f2);
                if (lane == 0) wcnt2[wid] = __popcll(ball);
            }
        }
        __syncthreads();   // A2: wcnt2 visible
        int cnt2 = 0, base2 = 0;
        #pragma unroll
        for (int w = 0; w < 8; ++w) {
            int c = wcnt2[w];
            if (w < (wid & 7)) base2 += c;
            cnt2 += c;
        }
        if (h == 0) {
            bool f2 = s2 > 0.f;
            unsigned long long ball = __ballot(f2);
            int pos = __popcll(ball & lt_mask);
            if (f2) list2[base2 + pos] = (short)j;
            int cntp = (cnt2 + 63) & ~63;
            if (j < cntp - cnt2) list2[cnt2 + j] = ZROW;
        }
        __syncthreads();   // B2: list2 ready

        // ---- Layer 3 gather: split-K across halves ----
        {
            int cntp = (cnt2 + 63) & ~63;
            int hsz = cntp >> 1;
            int s0 = h * hsz, e0 = s0 + hsz;
            float a[8] = {0.f,0.f,0.f,0.f,0.f,0.f,0.f,0.f};
            if (k3) {
                int r = s0;
                for (; r + 64 <= e0; r += 64) gather64(list2 + r, Wp3, a);
                if (r < e0) gather32(list2 + r, Wp3, a);
            }
            float sx = ((a[0]+a[1])+(a[2]+a[3])) + ((a[4]+a[5])+(a[6]+a[7]));
            if (h) pacc[j] = sx;
            __syncthreads();   // C3: partials ready
            if (h == 0) {
                sx += pacc[j];
                float nm3 = mem3 * (0.2f * (1.f - s3)) + sx + b3v;
                if (k3) mem3 = nm3;
                bool f3 = k3 && (mem3 > 0.5f);
                s3 = f3 ? 1.f : 0.f;  c3 += s3;
            }
        }
        mb = mbn;
        // next-step list1 scatter is fenced by A1/B1; pacc reuse fenced by C2/B2
    }

    // ---- epilogue (h0 threads own the results) ----
    const float inv_t = 1.f / (float)T_STEPS;
    if (h == 0) {
        out[OFF_FR1 + n * H + j] = c1 * inv_t;
        out[OFF_FR2 + n * H + j] = c2 * inv_t;
        out[OFF_FR3 + n * H + j] = c3 * inv_t;
    }

    if (tid < 16) acc10[tid] = 0.f;
    if (tid < 3)  rsum[tid] = 0.f;
    __syncthreads();

    if (h == 0) {
        for (int o = 0; o < OUTC; ++o) {
            float v = c3 * W4[o * H + j];
            for (int m = 32; m; m >>= 1) v += __shfl_xor(v, m, 64);
            if (lane == 0) atomicAdd(&acc10[o], v);
        }
        float v1 = c1, v2 = c2, v3 = c3;
        for (int m = 32; m; m >>= 1) {
            v1 += __shfl_xor(v1, m, 64);
            v2 += __shfl_xor(v2, m, 64);
            v3 += __shfl_xor(v3, m, 64);
        }
        if (lane == 0) {
            atomicAdd(&rsum[0], v1);
            atomicAdd(&rsum[1], v2);
            atomicAdd(&rsum[2], v3);
        }
    }
    __syncthreads();
    if (tid < OUTC) out[OFF_OUT + n * OUTC + tid] = acc10[tid] * inv_t + b4[tid];
    if (tid == 0) {
        const float sc = 1.f / ((float)NBATCH * (float)H * (float)T_STEPS);
        atomicAdd(&out[OFF_LFR + 0], rsum[0] * sc);
        atomicAdd(&out[OFF_LFR + 1], rsum[1] * sc);
        atomicAdd(&out[OFF_LFR + 2], rsum[2] * sc);
    }
}

extern "C" void kernel_launch(void* const* d_in, const int* in_sizes, int n_in,
                              void* d_out, int out_size, void* d_ws, size_t ws_size,
                              hipStream_t stream)
{
    const float* x  = (const float*)d_in[0];
    const float* W1 = (const float*)d_in[1];
    const float* b1 = (const float*)d_in[2];
    const float* W2 = (const float*)d_in[3];
    const float* b2 = (const float*)d_in[4];
    const float* W3 = (const float*)d_in[5];
    const float* b3 = (const float*)d_in[6];
    const float* W4 = (const float*)d_in[7];
    const float* b4 = (const float*)d_in[8];
    const float* m1 = (const float*)d_in[9];
    const float* m2 = (const float*)d_in[10];
    const float* m3 = (const float*)d_in[11];
    float* out = (float*)d_out;

    float* W2T = (float*)d_ws;                       // (H+1) x H
    float* W3T = W2T + (H + 1) * H;                  // (H+1) x H
    unsigned char* mP = (unsigned char*)(W3T + (H + 1) * H);

    hipLaunchKernelGGL(prep_kernel, dim3(512), dim3(256), 0, stream,
                       W2, W3, m1, m2, m3, W2T, W3T, mP, out + OFF_LFR);
    hipLaunchKernelGGL(snn_kernel, dim3(NBATCH), dim3(1024), 0, stream,
                       x, W1, b1, b2, b3, W4, b4, W2T, W3T, mP, out);
}

// Round 6
// 3279.134 us; speedup vs baseline: 2.5146x; 2.5146x over previous
//
#include <hip/hip_runtime.h>

#define T_STEPS 784
#define H 512
#define NBATCH 128
#define OUTC 10
#define ZROW 512   // zero-row index appended to W2T/W3T

// out layout (floats): outputs[128*10] | fr1[128*512] | fr2 | fr3 | layer_fr[3]
#define OFF_OUT   0
#define OFF_FR1   1280
#define OFF_FR2   66816
#define OFF_FR3   132352
#define OFF_LFR   197888

__global__ __launch_bounds__(256) void prep_kernel(
    const float* __restrict__ W2, const float* __restrict__ W3,
    const float* __restrict__ m1, const float* __restrict__ m2, const float* __restrict__ m3,
    float* __restrict__ W2T, float* __restrict__ W3T,
    unsigned char* __restrict__ mP, float* __restrict__ out_tail)
{
    int tid = blockIdx.x * blockDim.x + threadIdx.x;
    int stride = gridDim.x * blockDim.x;
    for (int p = tid; p < H * H; p += stride) {
        int i = p >> 9, j = p & (H - 1);
        W2T[p] = W2[j * H + i];
        W3T[p] = W3[j * H + i];
    }
    for (int p = tid; p < H; p += stride) {
        W2T[H * H + p] = 0.f;
        W3T[H * H + p] = 0.f;
    }
    for (int p = tid; p < T_STEPS * H; p += stride) {
        int t = p >> 9, i = p & (H - 1);
        unsigned char b = 0;
        if (m1[i * T_STEPS + t] != 0.f) b |= 1;
        if (m2[i * T_STEPS + t] != 0.f) b |= 2;
        if (m3[i * T_STEPS + t] != 0.f) b |= 4;
        mP[p] = b;
    }
    if (tid < 3) out_tail[tid] = 0.f;
}

// one round: 32 gathered floats (8 short4 list reads, 32 global loads in flight)
__device__ __forceinline__ void gather32(const short* lp, const float* __restrict__ Wp,
                                         float* a)
{
    const short4* q = (const short4*)lp;
    float g[32];
    #pragma unroll
    for (int i = 0; i < 8; ++i) {
        short4 s = q[i];
        g[4*i+0] = Wp[(int)s.x << 9];
        g[4*i+1] = Wp[(int)s.y << 9];
        g[4*i+2] = Wp[(int)s.z << 9];
        g[4*i+3] = Wp[(int)s.w << 9];
    }
    #pragma unroll
    for (int i = 0; i < 32; ++i) a[i & 7] += g[i];
}

__global__ __launch_bounds__(1024) void snn_kernel(
    const float* __restrict__ x,
    const float* __restrict__ W1, const float* __restrict__ b1,
    const float* __restrict__ b2, const float* __restrict__ b3,
    const float* __restrict__ W4, const float* __restrict__ b4,
    const float* __restrict__ W2T, const float* __restrict__ W3T,
    const unsigned char* __restrict__ mP,
    float* __restrict__ out)
{
    const int n = blockIdx.x;          // sample
    const int tid = threadIdx.x;
    const int h = tid >> 9;            // half: 0 or 1 (split-K over firing list)
    const int j = tid & (H - 1);       // neuron
    const int lane = tid & 63;
    const int wid = tid >> 6;          // 0..15; h==0 <=> wid<8

    __shared__ float x_lds[T_STEPS];
    __shared__ short list1[H + 64];
    __shared__ short list2[H + 64];
    __shared__ int wcnt1[8], wcnt2[8];
    __shared__ float pacc[H];
    __shared__ float acc10[16];
    __shared__ float rsum[3];

    for (int t = tid; t < T_STEPS; t += 1024) x_lds[t] = x[n * T_STEPS + t];

    float mem1 = 0.f, mem2 = 0.f, mem3 = 0.f;
    float s1 = 0.f, s2 = 0.f, s3 = 0.f;
    float c1 = 0.f, c2 = 0.f, c3 = 0.f;
    float w1 = 0.f, b1v = 0.f, b2v = 0.f, b3v = 0.f;
    if (h == 0) { w1 = W1[j]; b1v = b1[j]; b2v = b2[j]; b3v = b3[j]; }
    const unsigned long long lt_mask = (1ull << lane) - 1ull;
    const float* __restrict__ Wp2 = W2T + j;
    const float* __restrict__ Wp3 = W3T + j;

    unsigned char mb = mP[j];   // masks for t=0 (both halves read same byte)
    __syncthreads();

    for (int t = 0; t < T_STEPS; ++t) {
        const bool k1 = (mb & 1) != 0;
        const bool k2 = (mb & 2) != 0;
        const bool k3 = (mb & 4) != 0;

        // ---- Layer 1 (elementwise, h0 only) ----
        if (h == 0) {
            float nm1 = mem1 * (0.2f * (1.f - s1)) + x_lds[t] * w1 + b1v;
            if (k1) mem1 = nm1;
            bool f1 = k1 && (mem1 > 0.5f);
            s1 = f1 ? 1.f : 0.f;  c1 += s1;
            unsigned long long ball = __ballot(f1);
            if (lane == 0) wcnt1[wid] = __popcll(ball);
        }
        // prefetch next step's masks (flies under the gathers)
        int tn = (t + 1 < T_STEPS) ? t + 1 : t;
        unsigned char mbn = mP[tn * H + j];

        __syncthreads();   // A1: wcnt1 visible
        int cnt1 = 0, base1 = 0;
        #pragma unroll
        for (int w = 0; w < 8; ++w) {
            int c = wcnt1[w];
            if (w < (wid & 7)) base1 += c;
            cnt1 += c;
        }
        if (h == 0) {
            bool f1 = s1 > 0.f;
            unsigned long long ball = __ballot(f1);
            int pos = __popcll(ball & lt_mask);
            if (f1) list1[base1 + pos] = (short)j;
            int cntp = (cnt1 + 63) & ~63;
            if (j < cntp - cnt1) list1[cnt1 + j] = ZROW;
        }
        __syncthreads();   // B1: list1 ready (padded to x64)

        // ---- Layer 2 gather: split-K across halves ----
        {
            int hsz = ((cnt1 + 63) & ~63) >> 1;   // multiple of 32
            int s0 = h * hsz, e0 = s0 + hsz;
            float a[8] = {0.f,0.f,0.f,0.f,0.f,0.f,0.f,0.f};
            if (k2) {
                for (int r = s0; r < e0; r += 32) gather32(list1 + r, Wp2, a);
            }
            float sx = ((a[0]+a[1])+(a[2]+a[3])) + ((a[4]+a[5])+(a[6]+a[7]));
            if (h) pacc[j] = sx;
            __syncthreads();   // C2: partials ready
            if (h == 0) {
                sx += pacc[j];
                float nm2 = mem2 * (0.2f * (1.f - s2)) + sx + b2v;
                if (k2) mem2 = nm2;
                bool f2 = k2 && (mem2 > 0.5f);
                s2 = f2 ? 1.f : 0.f;  c2 += s2;
                unsigned long long ball = __ballot(f2);
                if (lane == 0) wcnt2[wid] = __popcll(ball);
            }
        }
        __syncthreads();   // A2: wcnt2 visible
        int cnt2 = 0, base2 = 0;
        #pragma unroll
        for (int w = 0; w < 8; ++w) {
            int c = wcnt2[w];
            if (w < (wid & 7)) base2 += c;
            cnt2 += c;
        }
        if (h == 0) {
            bool f2 = s2 > 0.f;
            unsigned long long ball = __ballot(f2);
            int pos = __popcll(ball & lt_mask);
            if (f2) list2[base2 + pos] = (short)j;
            int cntp = (cnt2 + 63) & ~63;
            if (j < cntp - cnt2) list2[cnt2 + j] = ZROW;
        }
        __syncthreads();   // B2: list2 ready

        // ---- Layer 3 gather: split-K across halves ----
        {
            int hsz = ((cnt2 + 63) & ~63) >> 1;
            int s0 = h * hsz, e0 = s0 + hsz;
            float a[8] = {0.f,0.f,0.f,0.f,0.f,0.f,0.f,0.f};
            if (k3) {
                for (int r = s0; r < e0; r += 32) gather32(list2 + r, Wp3, a);
            }
            float sx = ((a[0]+a[1])+(a[2]+a[3])) + ((a[4]+a[5])+(a[6]+a[7]));
            if (h) pacc[j] = sx;
            __syncthreads();   // C3: partials ready
            if (h == 0) {
                sx += pacc[j];
                float nm3 = mem3 * (0.2f * (1.f - s3)) + sx + b3v;
                if (k3) mem3 = nm3;
                bool f3 = k3 && (mem3 > 0.5f);
                s3 = f3 ? 1.f : 0.f;  c3 += s3;
            }
        }
        mb = mbn;
        // next-step list1 scatter fenced by A1/B1; pacc reuse fenced by C2/B2
    }

    // ---- epilogue (h0 threads own the results) ----
    const float inv_t = 1.f / (float)T_STEPS;
    if (h == 0) {
        out[OFF_FR1 + n * H + j] = c1 * inv_t;
        out[OFF_FR2 + n * H + j] = c2 * inv_t;
        out[OFF_FR3 + n * H + j] = c3 * inv_t;
    }

    if (tid < 16) acc10[tid] = 0.f;
    if (tid < 3)  rsum[tid] = 0.f;
    __syncthreads();

    if (h == 0) {
        for (int o = 0; o < OUTC; ++o) {
            float v = c3 * W4[o * H + j];
            for (int m = 32; m; m >>= 1) v += __shfl_xor(v, m, 64);
            if (lane == 0) atomicAdd(&acc10[o], v);
        }
        float v1 = c1, v2 = c2, v3 = c3;
        for (int m = 32; m; m >>= 1) {
            v1 += __shfl_xor(v1, m, 64);
            v2 += __shfl_xor(v2, m, 64);
            v3 += __shfl_xor(v3, m, 64);
        }
        if (lane == 0) {
            atomicAdd(&rsum[0], v1);
            atomicAdd(&rsum[1], v2);
            atomicAdd(&rsum[2], v3);
        }
    }
    __syncthreads();
    if (tid < OUTC) out[OFF_OUT + n * OUTC + tid] = acc10[tid] * inv_t + b4[tid];
    if (tid == 0) {
        const float sc = 1.f / ((float)NBATCH * (float)H * (float)T_STEPS);
        atomicAdd(&out[OFF_LFR + 0], rsum[0] * sc);
        atomicAdd(&out[OFF_LFR + 1], rsum[1] * sc);
        atomicAdd(&out[OFF_LFR + 2], rsum[2] * sc);
    }
}

extern "C" void kernel_launch(void* const* d_in, const int* in_sizes, int n_in,
                              void* d_out, int out_size, void* d_ws, size_t ws_size,
                              hipStream_t stream)
{
    const float* x  = (const float*)d_in[0];
    const float* W1 = (const float*)d_in[1];
    const float* b1 = (const float*)d_in[2];
    const float* W2 = (const float*)d_in[3];
    const float* b2 = (const float*)d_in[4];
    const float* W3 = (const float*)d_in[5];
    const float* b3 = (const float*)d_in[6];
    const float* W4 = (const float*)d_in[7];
    const float* b4 = (const float*)d_in[8];
    const float* m1 = (const float*)d_in[9];
    const float* m2 = (const float*)d_in[10];
    const float* m3 = (const float*)d_in[11];
    float* out = (float*)d_out;

    float* W2T = (float*)d_ws;                       // (H+1) x H
    float* W3T = W2T + (H + 1) * H;                  // (H+1) x H
    unsigned char* mP = (unsigned char*)(W3T + (H + 1) * H);

    hipLaunchKernelGGL(prep_kernel, dim3(512), dim3(256), 0, stream,
                       W2, W3, m1, m2, m3, W2T, W3T, mP, out + OFF_LFR);
    hipLaunchKernelGGL(snn_kernel, dim3(NBATCH), dim3(1024), 0, stream,
                       x, W1, b1, b2, b3, W4, b4, W2T, W3T, mP, out);
}

// Round 7
// 3201.250 us; speedup vs baseline: 2.5758x; 1.0243x over previous
//
#include <hip/hip_runtime.h>

#define T_STEPS 784
#define H 512
#define NBATCH 128
#define OUTC 10
#define ZROW 512   // zero-row index appended to W2T/W3T

// out layout (floats): outputs[128*10] | fr1[128*512] | fr2 | fr3 | layer_fr[3]
#define OFF_OUT   0
#define OFF_FR1   1280
#define OFF_FR2   66816
#define OFF_FR3   132352
#define OFF_LFR   197888

__global__ __launch_bounds__(256) void prep_kernel(
    const float* __restrict__ W2, const float* __restrict__ W3,
    const float* __restrict__ m1, const float* __restrict__ m2, const float* __restrict__ m3,
    float* __restrict__ W2T, float* __restrict__ W3T,
    unsigned char* __restrict__ mP, float* __restrict__ out_tail)
{
    int tid = blockIdx.x * blockDim.x + threadIdx.x;
    int stride = gridDim.x * blockDim.x;
    for (int p = tid; p < H * H; p += stride) {
        int i = p >> 9, j = p & (H - 1);
        W2T[p] = W2[j * H + i];
        W3T[p] = W3[j * H + i];
    }
    for (int p = tid; p < H; p += stride) {
        W2T[H * H + p] = 0.f;
        W3T[H * H + p] = 0.f;
    }
    for (int p = tid; p < T_STEPS * H; p += stride) {
        int t = p >> 9, i = p & (H - 1);
        unsigned char b = 0;
        if (m1[i * T_STEPS + t] != 0.f) b |= 1;
        if (m2[i * T_STEPS + t] != 0.f) b |= 2;
        if (m3[i * T_STEPS + t] != 0.f) b |= 4;
        mP[p] = b;
    }
    if (tid < 3) out_tail[tid] = 0.f;
}

__global__ __launch_bounds__(1024) void snn_kernel(
    const float* __restrict__ x,
    const float* __restrict__ W1, const float* __restrict__ b1,
    const float* __restrict__ b2, const float* __restrict__ b3,
    const float* __restrict__ W4, const float* __restrict__ b4,
    const float* __restrict__ W2T, const float* __restrict__ W3T,
    const unsigned char* __restrict__ mP,
    float* __restrict__ out)
{
    const int n = blockIdx.x;
    const int tid = threadIdx.x;
    const int lane = tid & 63;
    const int wid = tid >> 6;          // 0..15
    const int kg = tid >> 7;           // gather k-group 0..7
    const int g = tid & 127;           // column group: cols 4g..4g+3
    const bool upd = tid < H;          // neuron-owner role (j = tid)

    __shared__ float x_lds[T_STEPS];
    __shared__ float pacc[8 * H];      // 16 KB partials
    __shared__ short list1[H + 32];
    __shared__ short list2[H + 32];
    __shared__ int wcnt1[8], wcnt2[8];
    __shared__ float acc10[16];
    __shared__ float rsum[3];

    for (int t = tid; t < T_STEPS; t += 1024) x_lds[t] = x[n * T_STEPS + t];

    float mem1 = 0.f, mem2 = 0.f, mem3 = 0.f;
    float s1 = 0.f, s2 = 0.f, s3 = 0.f;
    float c1 = 0.f, c2 = 0.f, c3 = 0.f;
    float w1 = 0.f, b1v = 0.f, b2v = 0.f, b3v = 0.f;
    if (upd) { w1 = W1[tid]; b1v = b1[tid]; b2v = b2[tid]; b3v = b3[tid]; }
    const unsigned long long lt = (1ull << lane) - 1ull;
    const float4* __restrict__ Wg2 = (const float4*)W2T + g;  // row i -> Wg2[i<<7]
    const float4* __restrict__ Wg3 = (const float4*)W3T + g;

    unsigned char mb = upd ? mP[tid] : (unsigned char)0;       // own-neuron mask bits
    unsigned int  mw = ((const unsigned int*)mP)[g];           // 4 col-neurons' bytes

    __syncthreads();   // x_lds ready

    for (int t = 0; t < T_STEPS; ++t) {
        // ---- phase 1: layer-1 update (upd waves), mask prefetch (all) ----
        bool k2 = false, k3 = false;
        if (upd) {
            k2 = (mb & 2) != 0;
            k3 = (mb & 4) != 0;
            float nm = mem1 * (0.2f * (1.f - s1)) + x_lds[t] * w1 + b1v;
            if (mb & 1) mem1 = nm;
            bool f1 = (mb & 1) && (mem1 > 0.5f);
            s1 = f1 ? 1.f : 0.f;  c1 += s1;
            unsigned long long ball = __ballot(f1);
            if (lane == 0) wcnt1[wid] = __popcll(ball);
        }
        const bool g2any = (mw & 0x02020202u) != 0u;
        const bool g3any = (mw & 0x04040404u) != 0u;
        int tn = (t + 1 < T_STEPS) ? t + 1 : t;
        unsigned char mbn = upd ? mP[tn * H + tid] : (unsigned char)0;
        unsigned int  mwn = ((const unsigned int*)(mP + tn * H))[g];

        __syncthreads();   // A1: wcnt1 visible

        int cnt1 = 0, base1 = 0;
        #pragma unroll
        for (int w = 0; w < 8; ++w) {
            int c = wcnt1[w];
            if (w < wid) base1 += c;
            cnt1 += c;
        }
        if (upd) {
            bool f1 = s1 > 0.f;
            unsigned long long ball = __ballot(f1);
            if (f1) list1[base1 + __popcll(ball & lt)] = (short)tid;
        }
        __syncthreads();   // B1: list1 ready

        // ---- gather W2 (K8 split, float4 cols) ----
        {
            int share = ((cnt1 + 31) & ~31) >> 3;     // multiple of 4
            int s0 = kg * share;
            int rlim = min(s0 + share, cnt1);
            float4 aA = make_float4(0.f, 0.f, 0.f, 0.f);
            float4 aB = make_float4(0.f, 0.f, 0.f, 0.f);
            if (g2any) {
                for (int r = s0; r < s0 + share; r += 8) {
                    short4 sa = *(const short4*)(list1 + r);
                    short4 sb = *(const short4*)(list1 + r + 4);
                    int i0 = (r + 0 < rlim) ? (int)sa.x : ZROW;
                    int i1 = (r + 1 < rlim) ? (int)sa.y : ZROW;
                    int i2 = (r + 2 < rlim) ? (int)sa.z : ZROW;
                    int i3 = (r + 3 < rlim) ? (int)sa.w : ZROW;
                    int i4 = (r + 4 < rlim) ? (int)sb.x : ZROW;
                    int i5 = (r + 5 < rlim) ? (int)sb.y : ZROW;
                    int i6 = (r + 6 < rlim) ? (int)sb.z : ZROW;
                    int i7 = (r + 7 < rlim) ? (int)sb.w : ZROW;
                    float4 g0 = Wg2[i0 << 7];
                    float4 g1 = Wg2[i1 << 7];
                    float4 g2 = Wg2[i2 << 7];
                    float4 g3 = Wg2[i3 << 7];
                    float4 g4 = Wg2[i4 << 7];
                    float4 g5 = Wg2[i5 << 7];
                    float4 g6 = Wg2[i6 << 7];
                    float4 g7 = Wg2[i7 << 7];
                    aA.x += g0.x; aA.y += g0.y; aA.z += g0.z; aA.w += g0.w;
                    aB.x += g1.x; aB.y += g1.y; aB.z += g1.z; aB.w += g1.w;
                    aA.x += g2.x; aA.y += g2.y; aA.z += g2.z; aA.w += g2.w;
                    aB.x += g3.x; aB.y += g3.y; aB.z += g3.z; aB.w += g3.w;
                    aA.x += g4.x; aA.y += g4.y; aA.z += g4.z; aA.w += g4.w;
                    aB.x += g5.x; aB.y += g5.y; aB.z += g5.z; aB.w += g5.w;
                    aA.x += g6.x; aA.y += g6.y; aA.z += g6.z; aA.w += g6.w;
                    aB.x += g7.x; aB.y += g7.y; aB.z += g7.z; aB.w += g7.w;
                }
            }
            float4 s4;
            s4.x = aA.x + aB.x; s4.y = aA.y + aB.y;
            s4.z = aA.z + aB.z; s4.w = aA.w + aB.w;
            ((float4*)pacc)[(kg << 7) + g] = s4;
        }
        __syncthreads();   // C1: partials ready

        // ---- reduce + layer-2 update ----
        if (upd) {
            float p0 = pacc[tid]           + pacc[H + tid];
            float p1 = pacc[2 * H + tid]   + pacc[3 * H + tid];
            float p2 = pacc[4 * H + tid]   + pacc[5 * H + tid];
            float p3 = pacc[6 * H + tid]   + pacc[7 * H + tid];
            float sx = (p0 + p1) + (p2 + p3);
            float nm = mem2 * (0.2f * (1.f - s2)) + sx + b2v;
            if (k2) mem2 = nm;
            bool f2 = k2 && (mem2 > 0.5f);
            s2 = f2 ? 1.f : 0.f;  c2 += s2;
            unsigned long long ball = __ballot(f2);
            if (lane == 0) wcnt2[wid] = __popcll(ball);
        }
        __syncthreads();   // A2: wcnt2 visible

        int cnt2 = 0, base2 = 0;
        #pragma unroll
        for (int w = 0; w < 8; ++w) {
            int c = wcnt2[w];
            if (w < wid) base2 += c;
            cnt2 += c;
        }
        if (upd) {
            bool f2 = s2 > 0.f;
            unsigned long long ball = __ballot(f2);
            if (f2) list2[base2 + __popcll(ball & lt)] = (short)tid;
        }
        __syncthreads();   // B2: list2 ready

        // ---- gather W3 (K8 split, float4 cols) ----
        {
            int share = ((cnt2 + 31) & ~31) >> 3;
            int s0 = kg * share;
            int rlim = min(s0 + share, cnt2);
            float4 aA = make_float4(0.f, 0.f, 0.f, 0.f);
            float4 aB = make_float4(0.f, 0.f, 0.f, 0.f);
            if (g3any) {
                for (int r = s0; r < s0 + share; r += 8) {
                    short4 sa = *(const short4*)(list2 + r);
                    short4 sb = *(const short4*)(list2 + r + 4);
                    int i0 = (r + 0 < rlim) ? (int)sa.x : ZROW;
                    int i1 = (r + 1 < rlim) ? (int)sa.y : ZROW;
                    int i2 = (r + 2 < rlim) ? (int)sa.z : ZROW;
                    int i3 = (r + 3 < rlim) ? (int)sa.w : ZROW;
                    int i4 = (r + 4 < rlim) ? (int)sb.x : ZROW;
                    int i5 = (r + 5 < rlim) ? (int)sb.y : ZROW;
                    int i6 = (r + 6 < rlim) ? (int)sb.z : ZROW;
                    int i7 = (r + 7 < rlim) ? (int)sb.w : ZROW;
                    float4 g0 = Wg3[i0 << 7];
                    float4 g1 = Wg3[i1 << 7];
                    float4 g2 = Wg3[i2 << 7];
                    float4 g3 = Wg3[i3 << 7];
                    float4 g4 = Wg3[i4 << 7];
                    float4 g5 = Wg3[i5 << 7];
                    float4 g6 = Wg3[i6 << 7];
                    float4 g7 = Wg3[i7 << 7];
                    aA.x += g0.x; aA.y += g0.y; aA.z += g0.z; aA.w += g0.w;
                    aB.x += g1.x; aB.y += g1.y; aB.z += g1.z; aB.w += g1.w;
                    aA.x += g2.x; aA.y += g2.y; aA.z += g2.z; aA.w += g2.w;
                    aB.x += g3.x; aB.y += g3.y; aB.z += g3.z; aB.w += g3.w;
                    aA.x += g4.x; aA.y += g4.y; aA.z += g4.z; aA.w += g4.w;
                    aB.x += g5.x; aB.y += g5.y; aB.z += g5.z; aB.w += g5.w;
                    aA.x += g6.x; aA.y += g6.y; aA.z += g6.z; aA.w += g6.w;
                    aB.x += g7.x; aB.y += g7.y; aB.z += g7.z; aB.w += g7.w;
                }
            }
            float4 s4;
            s4.x = aA.x + aB.x; s4.y = aA.y + aB.y;
            s4.z = aA.z + aB.z; s4.w = aA.w + aB.w;
            ((float4*)pacc)[(kg << 7) + g] = s4;
        }
        __syncthreads();   // C2: partials ready

        // ---- reduce + layer-3 update (merged with next phase 1) ----
        if (upd) {
            float p0 = pacc[tid]           + pacc[H + tid];
            float p1 = pacc[2 * H + tid]   + pacc[3 * H + tid];
            float p2 = pacc[4 * H + tid]   + pacc[5 * H + tid];
            float p3 = pacc[6 * H + tid]   + pacc[7 * H + tid];
            float sx = (p0 + p1) + (p2 + p3);
            float nm = mem3 * (0.2f * (1.f - s3)) + sx + b3v;
            if (k3) mem3 = nm;
            bool f3 = k3 && (mem3 > 0.5f);
            s3 = f3 ? 1.f : 0.f;  c3 += s3;
        }
        mb = mbn;  mw = mwn;
    }

    // ---- epilogue ----
    const float inv_t = 1.f / (float)T_STEPS;
    if (upd) {
        out[OFF_FR1 + n * H + tid] = c1 * inv_t;
        out[OFF_FR2 + n * H + tid] = c2 * inv_t;
        out[OFF_FR3 + n * H + tid] = c3 * inv_t;
    }
    if (tid < 16) acc10[tid] = 0.f;
    if (tid < 3)  rsum[tid] = 0.f;
    __syncthreads();

    if (upd) {
        for (int o = 0; o < OUTC; ++o) {
            float v = c3 * W4[o * H + tid];
            for (int m = 32; m; m >>= 1) v += __shfl_xor(v, m, 64);
            if (lane == 0) atomicAdd(&acc10[o], v);
        }
        float v1 = c1, v2 = c2, v3 = c3;
        for (int m = 32; m; m >>= 1) {
            v1 += __shfl_xor(v1, m, 64);
            v2 += __shfl_xor(v2, m, 64);
            v3 += __shfl_xor(v3, m, 64);
        }
        if (lane == 0) {
            atomicAdd(&rsum[0], v1);
            atomicAdd(&rsum[1], v2);
            atomicAdd(&rsum[2], v3);
        }
    }
    __syncthreads();
    if (tid < OUTC) out[OFF_OUT + n * OUTC + tid] = acc10[tid] * inv_t + b4[tid];
    if (tid == 0) {
        const float sc = 1.f / ((float)NBATCH * (float)H * (float)T_STEPS);
        atomicAdd(&out[OFF_LFR + 0], rsum[0] * sc);
        atomicAdd(&out[OFF_LFR + 1], rsum[1] * sc);
        atomicAdd(&out[OFF_LFR + 2], rsum[2] * sc);
    }
}

extern "C" void kernel_launch(void* const* d_in, const int* in_sizes, int n_in,
                              void* d_out, int out_size, void* d_ws, size_t ws_size,
                              hipStream_t stream)
{
    const float* x  = (const float*)d_in[0];
    const float* W1 = (const float*)d_in[1];
    const float* b1 = (const float*)d_in[2];
    const float* W2 = (const float*)d_in[3];
    const float* b2 = (const float*)d_in[4];
    const float* W3 = (const float*)d_in[5];
    const float* b3 = (const float*)d_in[6];
    const float* W4 = (const float*)d_in[7];
    const float* b4 = (const float*)d_in[8];
    const float* m1 = (const float*)d_in[9];
    const float* m2 = (const float*)d_in[10];
    const float* m3 = (const float*)d_in[11];
    float* out = (float*)d_out;

    float* W2T = (float*)d_ws;                       // (H+1) x H
    float* W3T = W2T + (H + 1) * H;                  // (H+1) x H
    unsigned char* mP = (unsigned char*)(W3T + (H + 1) * H);

    hipLaunchKernelGGL(prep_kernel, dim3(512), dim3(256), 0, stream,
                       W2, W3, m1, m2, m3, W2T, W3T, mP, out + OFF_LFR);
    hipLaunchKernelGGL(snn_kernel, dim3(NBATCH), dim3(1024), 0, stream,
                       x, W1, b1, b2, b3, W4, b4, W2T, W3T, mP, out);
}